// Round 2
// baseline (503.794 us; speedup 1.0000x reference)
//
#include <hip/hip_runtime.h>
#include <hip/hip_bf16.h>
#include <stdint.h>

// BaseLayer MoE block. I/O is FLOAT32 (per reference); internal GEMM compute
// is bf16 MFMA. T=8192 tokens, D=1024, F=4096, E=8, C=1024.
// Pipeline: transpose+cast weights -> LN+scores -> balanced assignment
// (radix select, jax top_k tie semantics) -> GEMM1(+gelu) -> GEMM2(+res+scatter).

#define T_TOK 8192
#define DM    1024
#define FF    4096
#define NE    8
#define CAP   1024

typedef __attribute__((ext_vector_type(8))) __bf16 bf16x8;
typedef __attribute__((ext_vector_type(4))) float  f32x4;

__device__ __forceinline__ unsigned short f2bf(float f) {
  unsigned u = __float_as_uint(f);
  u += 0x7FFFu + ((u >> 16) & 1u);   // round-to-nearest-even
  return (unsigned short)(u >> 16);
}
__device__ __forceinline__ float bf2f(unsigned short u) {
  return __uint_as_float(((unsigned)u) << 16);
}
__device__ __forceinline__ void gload_lds16(const void* g, void* l) {
  __builtin_amdgcn_global_load_lds(
      (const __attribute__((address_space(1))) unsigned int*)(uintptr_t)g,
      (__attribute__((address_space(3))) unsigned int*)l, 16, 0, 0);
}

// ------- transpose+cast: src f32 [E][K][N] -> dst bf16 [E][N][K] ------------
__global__ __launch_bounds__(256) void transpose_cast(
    const float* __restrict__ src, unsigned short* __restrict__ dst,
    int K, int N) {
  __shared__ float t[64][65];
  const int e = blockIdx.z;
  const int n0 = blockIdx.x * 64, k0 = blockIdx.y * 64;
  const float* s = src + (size_t)e * K * N;
  unsigned short* d = dst + (size_t)e * N * K;
  const int tid = threadIdx.x;
  for (int p = tid; p < 1024; p += 256) {           // 64x64 f32, float4 loads
    int r = p >> 4, c4 = (p & 15) * 4;
    float4 v = *(const float4*)(s + (size_t)(k0 + r) * N + n0 + c4);
    t[c4 + 0][r] = v.x; t[c4 + 1][r] = v.y;
    t[c4 + 2][r] = v.z; t[c4 + 3][r] = v.w;
  }
  __syncthreads();
  for (int p = tid; p < 512; p += 256) {            // 8 bf16 (16B) per op
    int c = p >> 3, r8 = (p & 7) * 8;
    unsigned short tmp[8];
#pragma unroll
    for (int i = 0; i < 8; ++i) tmp[i] = f2bf(t[c][r8 + i]);
    *(uint4*)(d + (size_t)(n0 + c) * K + k0 + r8) = *(const uint4*)tmp;
  }
}

// ---------------- LN + centroid scores (f32 in, bf16 nrm out) ---------------
__global__ __launch_bounds__(256) void ln_scores_k(
    const float* __restrict__ x, const float* __restrict__ g,
    const float* __restrict__ b, const float* __restrict__ cent,
    unsigned short* __restrict__ nrm, float* __restrict__ scores) {
  const int t = blockIdx.x, tid = threadIdx.x;
  const int lane = tid & 63, w = tid >> 6;
  float4 v = ((const float4*)(x + (size_t)t * DM))[tid];
  float f0 = v.x, f1 = v.y, f2 = v.z, f3 = v.w;
  float s = f0 + f1 + f2 + f3;
  float sq = f0 * f0 + f1 * f1 + f2 * f2 + f3 * f3;
#pragma unroll
  for (int o = 32; o > 0; o >>= 1) { s += __shfl_xor(s, o); sq += __shfl_xor(sq, o); }
  __shared__ float red[8];
  if (lane == 0) { red[w] = s; red[4 + w] = sq; }
  __syncthreads();
  float S = red[0] + red[1] + red[2] + red[3];
  float SQ = red[4] + red[5] + red[6] + red[7];
  float mu = S * (1.0f / DM);
  float var = SQ * (1.0f / DM) - mu * mu;
  float rstd = rsqrtf(var + 1e-5f);
  float4 gv = ((const float4*)g)[tid];
  float4 bv = ((const float4*)b)[tid];
  float n0 = (f0 - mu) * rstd * gv.x + bv.x;
  float n1 = (f1 - mu) * rstd * gv.y + bv.y;
  float n2 = (f2 - mu) * rstd * gv.z + bv.z;
  float n3 = (f3 - mu) * rstd * gv.w + bv.w;
  ushort4 o4;
  o4.x = f2bf(n0); o4.y = f2bf(n1); o4.z = f2bf(n2); o4.w = f2bf(n3);
  ((ushort4*)(nrm + (size_t)t * DM))[tid] = o4;
  __shared__ float sred[4];
  for (int e = 0; e < NE; ++e) {
    float4 cv = ((const float4*)(cent + e * DM))[tid];
    float p = n0 * cv.x + n1 * cv.y + n2 * cv.z + n3 * cv.w;
#pragma unroll
    for (int o = 32; o > 0; o >>= 1) p += __shfl_xor(p, o);
    if (lane == 0) sred[w] = p;
    __syncthreads();
    if (tid == 0) scores[(size_t)t * NE + e] = sred[0] + sred[1] + sred[2] + sred[3];
    __syncthreads();
  }
}

// ---------------- balanced assignment (greedy per expert, exact top_k) ------
__global__ __launch_bounds__(1024) void assign_k(const float* __restrict__ scores,
                                                 int* __restrict__ tok) {
  __shared__ unsigned key[T_TOK];
  __shared__ unsigned char taken[T_TOK];
  __shared__ unsigned hist[256];
  __shared__ unsigned scan[256];
  __shared__ unsigned wsum[16];
  __shared__ unsigned prefS, needS, cntS, remS;
  const int tid = threadIdx.x, lane = tid & 63, w = tid >> 6;
  for (int i = tid; i < T_TOK; i += 1024) taken[i] = 0;
  __syncthreads();
  for (int e = 0; e < NE; ++e) {
    for (int i = tid; i < T_TOK; i += 1024) {
      unsigned k = 0;
      if (!taken[i]) {
        unsigned bb = __float_as_uint(scores[(size_t)i * NE + e]);
        k = (bb & 0x80000000u) ? ~bb : (bb | 0x80000000u);  // order-preserving
      }
      key[i] = k;
    }
    if (tid == 0) { prefS = 0u; needS = CAP; cntS = 0u; }
    __syncthreads();
#pragma unroll
    for (int pass = 0; pass < 4; ++pass) {
      const int shift = 24 - 8 * pass;
      if (tid < 256) hist[tid] = 0u;
      unsigned pref = prefS, need = needS;
      unsigned hmask = (pass == 0) ? 0u : (0xFFFFFFFFu << (shift + 8));
      __syncthreads();
      for (int i = tid; i < T_TOK; i += 1024) {
        unsigned k = key[i];
        if ((k & hmask) == (pref & hmask)) atomicAdd(&hist[(k >> shift) & 255u], 1u);
      }
      __syncthreads();
      if (tid < 256) scan[tid] = hist[tid];
      __syncthreads();
      for (int off2 = 1; off2 < 256; off2 <<= 1) {   // suffix inclusive scan
        unsigned vv = 0;
        if (tid < 256) { vv = scan[tid]; if (tid + off2 < 256) vv += scan[tid + off2]; }
        __syncthreads();
        if (tid < 256) scan[tid] = vv;
        __syncthreads();
      }
      if (tid < 256) {
        unsigned incl = scan[tid], excl = incl - hist[tid];
        if (excl < need && incl >= need) {
          prefS = (pref & hmask) | (((unsigned)tid) << shift);
          needS = need - excl;
        }
      }
      __syncthreads();
    }
    const unsigned P = prefS;
    const unsigned need = needS;
    // take all strictly greater than pivot (order within expert irrelevant)
    for (int i = tid; i < T_TOK; i += 1024) {
      if (key[i] > P) {
        unsigned pos = atomicAdd(&cntS, 1u);
        tok[e * CAP + pos] = i;
        taken[i] = 1;
      }
    }
    if (tid == 0) remS = need;
    __syncthreads();
    // take `need` of the ==pivot keys, by LOWEST token index (jax top_k ties)
    for (int ch = 0; ch < 8; ++ch) {
      int i = ch * 1024 + tid;
      bool flag = (key[i] == P);
      unsigned long long ball = __ballot(flag);
      if (lane == 0) wsum[w] = (unsigned)__popcll(ball);
      unsigned myc = (unsigned)__popcll(ball & ((1ull << lane) - 1ull));
      __syncthreads();
      unsigned base = 0, tot = 0;
      for (int j2 = 0; j2 < 16; ++j2) { unsigned u = wsum[j2]; tot += u; if (j2 < w) base += u; }
      unsigned rem = remS;
      if (flag && (base + myc) < rem) {
        unsigned pos = atomicAdd(&cntS, 1u);
        tok[e * CAP + pos] = i;
        taken[i] = 1;
      }
      __syncthreads();
      if (tid == 0) remS = (rem > tot) ? (rem - tot) : 0u;
      __syncthreads();
    }
    __syncthreads();
  }
}

// ---------------- MFMA GEMM: C = A[MxK] * Bt[NxK]^T, fused epilogues --------
// EPI==1: +bias, gelu(tanh) -> h1 bf16 (row = e*CAP+m)
// EPI==2: +bias, +residual x[token] (f32), scatter -> out f32 [token]
template <int EPI, bool GATHER, int K, int N>
__global__ __launch_bounds__(256) void gemm_ffn(
    const unsigned short* __restrict__ A, const unsigned short* __restrict__ Bt,
    const float* __restrict__ bias, const int* __restrict__ tok,
    const float* __restrict__ xres, void* __restrict__ Cout) {
  constexpr int BM = 128, BN = 128, BK = 64;
  __shared__ __align__(16) unsigned short Als[BM * BK];
  __shared__ __align__(16) unsigned short Bls[BN * BK];
  __shared__ int tokl[BM];
  const int e = blockIdx.z;
  const int n0 = blockIdx.x * BN, m0 = blockIdx.y * BM;
  const int tid = threadIdx.x, lane = tid & 63, w = tid >> 6;
  const int wr = w >> 1, wc = w & 1;
  if (tid < BM) tokl[tid] = tok[e * CAP + m0 + tid];
  __syncthreads();

  const unsigned short* Be = Bt + (size_t)e * N * K + (size_t)n0 * K;
  f32x4 acc[4][4] = {};

  for (int kt = 0; kt < K; kt += BK) {
    // stage A tile [128 rows][64 k] bf16: linear LDS dest, XOR-swizzled source
#pragma unroll
    for (int i = 0; i < 4; ++i) {
      int l = i * 256 + tid;
      int row = l >> 3, ps = l & 7;
      int ks = ps ^ (row & 7);
      const unsigned short* gp;
      if (GATHER) gp = A + (size_t)tokl[row] * K + kt + ks * 8;
      else        gp = A + (size_t)(e * CAP + m0 + row) * K + kt + ks * 8;
      gload_lds16(gp, Als + (size_t)l * 8);
    }
#pragma unroll
    for (int i = 0; i < 4; ++i) {
      int l = i * 256 + tid;
      int row = l >> 3, ps = l & 7;
      int ks = ps ^ (row & 7);
      gload_lds16(Be + (size_t)row * K + kt + ks * 8, Bls + (size_t)l * 8);
    }
    __syncthreads();  // drains vmcnt -> tiles visible to all waves
    {
      const int lr = lane & 15, lk = lane >> 4;
#pragma unroll
      for (int kk = 0; kk < 2; ++kk) {
        bf16x8 af[4], bfr[4];
#pragma unroll
        for (int mi = 0; mi < 4; ++mi) {
          int row = wr * 64 + mi * 16 + lr;
          int ks = (kk * 4 + lk) ^ (row & 7);
          af[mi] = *(const bf16x8*)(Als + row * 64 + ks * 8);
        }
#pragma unroll
        for (int ni = 0; ni < 4; ++ni) {
          int row = wc * 64 + ni * 16 + lr;
          int ks = (kk * 4 + lk) ^ (row & 7);
          bfr[ni] = *(const bf16x8*)(Bls + row * 64 + ks * 8);
        }
#pragma unroll
        for (int mi = 0; mi < 4; ++mi)
#pragma unroll
          for (int ni = 0; ni < 4; ++ni)
            acc[mi][ni] = __builtin_amdgcn_mfma_f32_16x16x32_bf16(
                af[mi], bfr[ni], acc[mi][ni], 0, 0, 0);
      }
    }
    __syncthreads();
  }

  const int lr = lane & 15, lg = lane >> 4;
#pragma unroll
  for (int ni = 0; ni < 4; ++ni) {
    int n = n0 + wc * 64 + ni * 16 + lr;
    float bb = bias[e * N + n];
#pragma unroll
    for (int mi = 0; mi < 4; ++mi) {
#pragma unroll
      for (int r = 0; r < 4; ++r) {
        int mrow = wr * 64 + mi * 16 + lg * 4 + r;
        float v = acc[mi][ni][r] + bb;
        if (EPI == 1) {
          float gl = 0.5f * v *
              (1.0f + tanhf(0.7978845608028654f * (v + 0.044715f * v * v * v)));
          ((unsigned short*)Cout)[(size_t)(e * CAP + m0 + mrow) * N + n] = f2bf(gl);
        } else {
          int token = tokl[mrow];
          v += xres[(size_t)token * DM + n];
          ((float*)Cout)[(size_t)token * (size_t)N + n] = v;
        }
      }
    }
  }
}

// ---------------- launch ----------------------------------------------------
extern "C" void kernel_launch(void* const* d_in, const int* in_sizes, int n_in,
                              void* d_out, int out_size, void* d_ws, size_t ws_size,
                              hipStream_t stream) {
  const float* x    = (const float*)d_in[0];
  const float* cent = (const float*)d_in[1];
  const float* ln_g = (const float*)d_in[2];
  const float* ln_b = (const float*)d_in[3];
  const float* w1   = (const float*)d_in[4];
  const float* b1   = (const float*)d_in[5];
  const float* w2   = (const float*)d_in[6];
  const float* b2   = (const float*)d_in[7];
  float* out = (float*)d_out;

  char* ws = (char*)d_ws;
  size_t off = 0;
  unsigned short* w1T = (unsigned short*)(ws + off); off += (size_t)NE * FF * DM * 2;
  unsigned short* w2T = (unsigned short*)(ws + off); off += (size_t)NE * DM * FF * 2;
  unsigned short* nrm = (unsigned short*)(ws + off); off += (size_t)T_TOK * DM * 2;
  unsigned short* h1  = (unsigned short*)(ws + off); off += (size_t)T_TOK * FF * 2;
  float* scores       = (float*)(ws + off);          off += (size_t)T_TOK * NE * 4;
  int* tok            = (int*)(ws + off);            off += (size_t)T_TOK * 4;

  // w1 [E][D][F] -> w1T [E][F][D];  w2 [E][F][D] -> w2T [E][D][F]
  transpose_cast<<<dim3(FF / 64, DM / 64, NE), 256, 0, stream>>>(w1, w1T, DM, FF);
  transpose_cast<<<dim3(DM / 64, FF / 64, NE), 256, 0, stream>>>(w2, w2T, FF, DM);
  ln_scores_k<<<dim3(T_TOK), 256, 0, stream>>>(x, ln_g, ln_b, cent, nrm, scores);
  assign_k<<<dim3(1), 1024, 0, stream>>>(scores, tok);
  gemm_ffn<1, true, DM, FF><<<dim3(FF / 128, CAP / 128, NE), 256, 0, stream>>>(
      nrm, w1T, b1, tok, nullptr, h1);
  gemm_ffn<2, false, FF, DM><<<dim3(DM / 128, CAP / 128, NE), 256, 0, stream>>>(
      h1, w2T, b2, tok, x, out);
}

// Round 3
// 502.430 us; speedup vs baseline: 1.0027x; 1.0027x over previous
//
#include <hip/hip_runtime.h>
#include <hip/hip_bf16.h>
#include <stdint.h>

// BaseLayer MoE block. I/O f32, GEMMs bf16 MFMA. T=8192, D=1024, F=4096, E=8.
// R3: ring-pipelined GEMM (BK=32, 4-deep LDS ring, counted vmcnt, raw s_barrier,
// 8 waves) replaces the 2-barrier vmcnt(0)-draining loop. Gelu via sigmoid.

#define T_TOK 8192
#define DM    1024
#define FF    4096
#define NE    8
#define CAP   1024

typedef __attribute__((ext_vector_type(8))) __bf16 bf16x8;
typedef __attribute__((ext_vector_type(4))) float  f32x4;

__device__ __forceinline__ unsigned short f2bf(float f) {
  unsigned u = __float_as_uint(f);
  u += 0x7FFFu + ((u >> 16) & 1u);   // round-to-nearest-even
  return (unsigned short)(u >> 16);
}
__device__ __forceinline__ void gload_lds16(const void* g, void* l) {
  __builtin_amdgcn_global_load_lds(
      (const __attribute__((address_space(1))) unsigned int*)(uintptr_t)g,
      (__attribute__((address_space(3))) unsigned int*)l, 16, 0, 0);
}
template <int V> __device__ __forceinline__ void wait_vm() {
  if constexpr (V == 0) asm volatile("s_waitcnt vmcnt(0)" ::: "memory");
  else if constexpr (V == 3) asm volatile("s_waitcnt vmcnt(3)" ::: "memory");
  else if constexpr (V == 4) asm volatile("s_waitcnt vmcnt(4)" ::: "memory");
  else if constexpr (V == 6) asm volatile("s_waitcnt vmcnt(6)" ::: "memory");
  else if constexpr (V == 8) asm volatile("s_waitcnt vmcnt(8)" ::: "memory");
}

// ------- transpose+cast: src f32 [E][K][N] -> dst bf16 [E][N][K] ------------
__global__ __launch_bounds__(256) void transpose_cast(
    const float* __restrict__ src, unsigned short* __restrict__ dst,
    int K, int N) {
  __shared__ float t[64][65];
  const int e = blockIdx.z;
  const int n0 = blockIdx.x * 64, k0 = blockIdx.y * 64;
  const float* s = src + (size_t)e * K * N;
  unsigned short* d = dst + (size_t)e * N * K;
  const int tid = threadIdx.x;
  for (int p = tid; p < 1024; p += 256) {
    int r = p >> 4, c4 = (p & 15) * 4;
    float4 v = *(const float4*)(s + (size_t)(k0 + r) * N + n0 + c4);
    t[c4 + 0][r] = v.x; t[c4 + 1][r] = v.y;
    t[c4 + 2][r] = v.z; t[c4 + 3][r] = v.w;
  }
  __syncthreads();
  for (int p = tid; p < 512; p += 256) {
    int c = p >> 3, r8 = (p & 7) * 8;
    unsigned short tmp[8];
#pragma unroll
    for (int i = 0; i < 8; ++i) tmp[i] = f2bf(t[c][r8 + i]);
    *(uint4*)(d + (size_t)(n0 + c) * K + k0 + r8) = *(const uint4*)tmp;
  }
}

// ---------------- LN + centroid scores (f32 in, bf16 nrm out) ---------------
__global__ __launch_bounds__(256) void ln_scores_k(
    const float* __restrict__ x, const float* __restrict__ g,
    const float* __restrict__ b, const float* __restrict__ cent,
    unsigned short* __restrict__ nrm, float* __restrict__ scores) {
  const int t = blockIdx.x, tid = threadIdx.x;
  const int lane = tid & 63, w = tid >> 6;
  float4 v = ((const float4*)(x + (size_t)t * DM))[tid];
  float f0 = v.x, f1 = v.y, f2 = v.z, f3 = v.w;
  float s = f0 + f1 + f2 + f3;
  float sq = f0 * f0 + f1 * f1 + f2 * f2 + f3 * f3;
#pragma unroll
  for (int o = 32; o > 0; o >>= 1) { s += __shfl_xor(s, o); sq += __shfl_xor(sq, o); }
  __shared__ float red[8];
  if (lane == 0) { red[w] = s; red[4 + w] = sq; }
  __syncthreads();
  float S = red[0] + red[1] + red[2] + red[3];
  float SQ = red[4] + red[5] + red[6] + red[7];
  float mu = S * (1.0f / DM);
  float var = SQ * (1.0f / DM) - mu * mu;
  float rstd = rsqrtf(var + 1e-5f);
  float4 gv = ((const float4*)g)[tid];
  float4 bv = ((const float4*)b)[tid];
  float n0 = (f0 - mu) * rstd * gv.x + bv.x;
  float n1 = (f1 - mu) * rstd * gv.y + bv.y;
  float n2 = (f2 - mu) * rstd * gv.z + bv.z;
  float n3 = (f3 - mu) * rstd * gv.w + bv.w;
  ushort4 o4;
  o4.x = f2bf(n0); o4.y = f2bf(n1); o4.z = f2bf(n2); o4.w = f2bf(n3);
  ((ushort4*)(nrm + (size_t)t * DM))[tid] = o4;
  __shared__ float sred[4];
  for (int e = 0; e < NE; ++e) {
    float4 cv = ((const float4*)(cent + e * DM))[tid];
    float p = n0 * cv.x + n1 * cv.y + n2 * cv.z + n3 * cv.w;
#pragma unroll
    for (int o = 32; o > 0; o >>= 1) p += __shfl_xor(p, o);
    if (lane == 0) sred[w] = p;
    __syncthreads();
    if (tid == 0) scores[(size_t)t * NE + e] = sred[0] + sred[1] + sred[2] + sred[3];
    __syncthreads();
  }
}

// ---------------- balanced assignment (greedy per expert, exact top_k) ------
__global__ __launch_bounds__(1024) void assign_k(const float* __restrict__ scores,
                                                 int* __restrict__ tok) {
  __shared__ unsigned key[T_TOK];
  __shared__ unsigned char taken[T_TOK];
  __shared__ unsigned hist[256];
  __shared__ unsigned scan[256];
  __shared__ unsigned wsum[16];
  __shared__ unsigned prefS, needS, cntS, remS;
  const int tid = threadIdx.x, lane = tid & 63, w = tid >> 6;
  for (int i = tid; i < T_TOK; i += 1024) taken[i] = 0;
  __syncthreads();
  for (int e = 0; e < NE; ++e) {
    for (int i = tid; i < T_TOK; i += 1024) {
      unsigned k = 0;
      if (!taken[i]) {
        unsigned bb = __float_as_uint(scores[(size_t)i * NE + e]);
        k = (bb & 0x80000000u) ? ~bb : (bb | 0x80000000u);  // order-preserving
      }
      key[i] = k;
    }
    if (tid == 0) { prefS = 0u; needS = CAP; cntS = 0u; }
    __syncthreads();
#pragma unroll
    for (int pass = 0; pass < 4; ++pass) {
      const int shift = 24 - 8 * pass;
      if (tid < 256) hist[tid] = 0u;
      unsigned pref = prefS, need = needS;
      unsigned hmask = (pass == 0) ? 0u : (0xFFFFFFFFu << (shift + 8));
      __syncthreads();
      for (int i = tid; i < T_TOK; i += 1024) {
        unsigned k = key[i];
        if ((k & hmask) == (pref & hmask)) atomicAdd(&hist[(k >> shift) & 255u], 1u);
      }
      __syncthreads();
      if (tid < 256) scan[tid] = hist[tid];
      __syncthreads();
      for (int off2 = 1; off2 < 256; off2 <<= 1) {   // suffix inclusive scan
        unsigned vv = 0;
        if (tid < 256) { vv = scan[tid]; if (tid + off2 < 256) vv += scan[tid + off2]; }
        __syncthreads();
        if (tid < 256) scan[tid] = vv;
        __syncthreads();
      }
      if (tid < 256) {
        unsigned incl = scan[tid], excl = incl - hist[tid];
        if (excl < need && incl >= need) {
          prefS = (pref & hmask) | (((unsigned)tid) << shift);
          needS = need - excl;
        }
      }
      __syncthreads();
    }
    const unsigned P = prefS;
    const unsigned need = needS;
    for (int i = tid; i < T_TOK; i += 1024) {
      if (key[i] > P) {
        unsigned pos = atomicAdd(&cntS, 1u);
        tok[e * CAP + pos] = i;
        taken[i] = 1;
      }
    }
    if (tid == 0) remS = need;
    __syncthreads();
    for (int ch = 0; ch < 8; ++ch) {   // ==pivot by lowest index (jax ties)
      int i = ch * 1024 + tid;
      bool flag = (key[i] == P);
      unsigned long long ball = __ballot(flag);
      if (lane == 0) wsum[w] = (unsigned)__popcll(ball);
      unsigned myc = (unsigned)__popcll(ball & ((1ull << lane) - 1ull));
      __syncthreads();
      unsigned base = 0, tot = 0;
      for (int j2 = 0; j2 < 16; ++j2) { unsigned u = wsum[j2]; tot += u; if (j2 < w) base += u; }
      unsigned rem = remS;
      if (flag && (base + myc) < rem) {
        unsigned pos = atomicAdd(&cntS, 1u);
        tok[e * CAP + pos] = i;
        taken[i] = 1;
      }
      __syncthreads();
      if (tid == 0) remS = (rem > tot) ? (rem - tot) : 0u;
      __syncthreads();
    }
    __syncthreads();
  }
}

// ------- ring-pipelined MFMA GEMM: C = A[MxK] * Bt[NxK]^T -------------------
// BK=32, 4-deep LDS ring, 1 raw barrier + counted vmcnt per K-tile.
// EPI==1: +bias, gelu -> bf16 h1;  EPI==2: +bias +xres, scatter f32 out.
template <int EPI, bool GATHER, int K, int N, int BM, int BN, int WM, int WN>
__global__ __launch_bounds__(512, 2) void gemm_pipe(
    const unsigned short* __restrict__ A, const unsigned short* __restrict__ Bt,
    const float* __restrict__ bias, const int* __restrict__ tok,
    const float* __restrict__ xres, void* __restrict__ Cout) {
  constexpr int NT   = K / 32;
  constexpr int RM   = BM / WM;          // per-wave rows
  constexpr int RN   = BN / WN;          // per-wave cols
  constexpr int MR   = RM / 16;
  constexpr int NR   = RN / 16;
  constexpr int AISS = BM / 128;         // gload_lds16 issues/thread for A
  constexpr int BISS = BN / 128;
  constexpr int ISS  = AISS + BISS;
  constexpr int SLOT = (BM + BN) * 32;   // shorts per ring slot
  __shared__ __align__(16) unsigned short lds[4 * SLOT];
  __shared__ int tokl[BM];

  const int e  = blockIdx.z;
  const int n0 = blockIdx.x * BN, m0 = blockIdx.y * BM;
  const int tid = threadIdx.x, lane = tid & 63, w = tid >> 6;
  const int wr = w / WN, wc = w % WN;
  const int lr = lane & 15, lk = lane >> 4;

  for (int i = tid; i < BM; i += 512) tokl[i] = tok[e * CAP + m0 + i];
  __syncthreads();

  // Per-thread fixed staging sources; LDS chunk c = row*4 + s' where
  // s' = s ^ ((row>>1)&3) (bank-spread, 2-way max = free).
  const unsigned short* aptr[AISS];
  const unsigned short* bptr[BISS];
  int aoff[AISS], boff[BISS];
  const unsigned short* Be = Bt + (size_t)e * N * K + (size_t)n0 * K;
#pragma unroll
  for (int i = 0; i < AISS; ++i) {
    int c = i * 512 + tid;
    int row = c >> 2, sp = c & 3;
    int s = sp ^ ((row >> 1) & 3);
    size_t grow = GATHER ? (size_t)tokl[row] : (size_t)(e * CAP + m0 + row);
    aptr[i] = A + grow * K + s * 8;
    aoff[i] = c * 8;
  }
#pragma unroll
  for (int i = 0; i < BISS; ++i) {
    int c = i * 512 + tid;
    int row = c >> 2, sp = c & 3;
    int s = sp ^ ((row >> 1) & 3);
    bptr[i] = Be + (size_t)row * K + s * 8;
    boff[i] = BM * 32 + c * 8;
  }
  // fragment read offset: k-chunk = lane>>4, same swizzle
  const int fsw = (lk ^ ((lr >> 1) & 3)) * 8 + lr * 32;

  f32x4 acc[MR][NR] = {};

  auto stage = [&](int t) {
    unsigned short* base = lds + (size_t)(t & 3) * SLOT;
    const int kb = t * 32;
#pragma unroll
    for (int i = 0; i < AISS; ++i) gload_lds16(aptr[i] + kb, base + aoff[i]);
#pragma unroll
    for (int i = 0; i < BISS; ++i) gload_lds16(bptr[i] + kb, base + boff[i]);
  };
  auto compute = [&](int t) {
    const unsigned short* base = lds + (size_t)(t & 3) * SLOT;
    bf16x8 af[MR], bfr[NR];
#pragma unroll
    for (int mi = 0; mi < MR; ++mi)
      af[mi] = *(const bf16x8*)(base + (wr * RM + mi * 16) * 32 + fsw);
#pragma unroll
    for (int ni = 0; ni < NR; ++ni)
      bfr[ni] = *(const bf16x8*)(base + BM * 32 + (wc * RN + ni * 16) * 32 + fsw);
#pragma unroll
    for (int mi = 0; mi < MR; ++mi)
#pragma unroll
      for (int ni = 0; ni < NR; ++ni)
        acc[mi][ni] = __builtin_amdgcn_mfma_f32_16x16x32_bf16(
            af[mi], bfr[ni], acc[mi][ni], 0, 0, 0);
  };

  stage(0); stage(1); stage(2);
#pragma unroll 1
  for (int t = 0; t < NT - 2; ++t) {
    wait_vm<2 * ISS>();                  // tile t landed (per-wave)...
    __builtin_amdgcn_s_barrier();        // ...and for every wave
    asm volatile("" ::: "memory");       // no LDS-read hoist above barrier
    if (t + 3 < NT) stage(t + 3);        // slot (t-1)&3, free since barrier
    compute(t);
  }
  wait_vm<ISS>();
  __builtin_amdgcn_s_barrier();
  asm volatile("" ::: "memory");
  compute(NT - 2);
  wait_vm<0>();
  __builtin_amdgcn_s_barrier();
  asm volatile("" ::: "memory");
  compute(NT - 1);

  // epilogue
  const int lg = lane >> 4;
#pragma unroll
  for (int ni = 0; ni < NR; ++ni) {
    const int n = n0 + wc * RN + ni * 16 + lr;
    const float bb = bias[e * N + n];
#pragma unroll
    for (int mi = 0; mi < MR; ++mi) {
#pragma unroll
      for (int r = 0; r < 4; ++r) {
        const int ml = wr * RM + mi * 16 + lg * 4 + r;
        float v = acc[mi][ni][r] + bb;
        if (EPI == 1) {
          // gelu(tanh) = v * sigmoid(1.59577v + 0.0713548v^3)
          float z = 1.5957691216f * v + 0.07135481283f * v * v * v;
          float gl = v / (1.0f + __expf(-z));
          ((unsigned short*)Cout)[(size_t)(e * CAP + m0 + ml) * N + n] = f2bf(gl);
        } else {
          const int token = tokl[ml];
          v += xres[(size_t)token * DM + n];
          ((float*)Cout)[(size_t)token * (size_t)N + n] = v;
        }
      }
    }
  }
}

// ---------------- launch ----------------------------------------------------
extern "C" void kernel_launch(void* const* d_in, const int* in_sizes, int n_in,
                              void* d_out, int out_size, void* d_ws, size_t ws_size,
                              hipStream_t stream) {
  const float* x    = (const float*)d_in[0];
  const float* cent = (const float*)d_in[1];
  const float* ln_g = (const float*)d_in[2];
  const float* ln_b = (const float*)d_in[3];
  const float* w1   = (const float*)d_in[4];
  const float* b1   = (const float*)d_in[5];
  const float* w2   = (const float*)d_in[6];
  const float* b2   = (const float*)d_in[7];
  float* out = (float*)d_out;

  char* ws = (char*)d_ws;
  size_t off = 0;
  unsigned short* w1T = (unsigned short*)(ws + off); off += (size_t)NE * FF * DM * 2;
  unsigned short* w2T = (unsigned short*)(ws + off); off += (size_t)NE * DM * FF * 2;
  unsigned short* nrm = (unsigned short*)(ws + off); off += (size_t)T_TOK * DM * 2;
  unsigned short* h1  = (unsigned short*)(ws + off); off += (size_t)T_TOK * FF * 2;
  float* scores       = (float*)(ws + off);          off += (size_t)T_TOK * NE * 4;
  int* tok            = (int*)(ws + off);            off += (size_t)T_TOK * 4;

  transpose_cast<<<dim3(FF / 64, DM / 64, NE), 256, 0, stream>>>(w1, w1T, DM, FF);
  transpose_cast<<<dim3(DM / 64, FF / 64, NE), 256, 0, stream>>>(w2, w2T, FF, DM);
  ln_scores_k<<<dim3(T_TOK), 256, 0, stream>>>(x, ln_g, ln_b, cent, nrm, scores);
  assign_k<<<dim3(1), 1024, 0, stream>>>(scores, tok);
  // GEMM1: [E] nrm-gather[1024x1024] x w1T[4096x1024]^T -> h1 (gelu)
  gemm_pipe<1, true, DM, FF, 256, 256, 2, 4>
      <<<dim3(FF / 256, CAP / 256, NE), 512, 0, stream>>>(nrm, w1T, b1, tok, nullptr, h1);
  // GEMM2: [E] h1[1024x4096] x w2T[1024x4096]^T -> out (+bias+res, scatter)
  gemm_pipe<2, false, FF, DM, 256, 128, 4, 2>
      <<<dim3(DM / 128, CAP / 256, NE), 512, 0, stream>>>(h1, w2T, b2, tok, x, out);
}

// Round 4
// 455.178 us; speedup vs baseline: 1.1068x; 1.1038x over previous
//
#include <hip/hip_runtime.h>
#include <hip/hip_bf16.h>
#include <stdint.h>

// BaseLayer MoE block. I/O f32, GEMMs bf16 MFMA. T=8192, D=1024, F=4096, E=8.
// R4: 8-phase interleaved GEMM schedule (T3+T4+T5): per phase {ds_read frags,
// stage half-tile, counted vmcnt @p3/p7, barrier, lgkmcnt(0), 8-16 MFMA,
// barrier}. 2 K-tiles (buf0/buf1) per iteration, BK=64 as 2 k-halves.

#define T_TOK 8192
#define DM    1024
#define FF    4096
#define NE    8
#define CAP   1024

typedef __attribute__((ext_vector_type(8))) __bf16 bf16x8;
typedef __attribute__((ext_vector_type(4))) float  f32x4;

__device__ __forceinline__ unsigned short f2bf(float f) {
  unsigned u = __float_as_uint(f);
  u += 0x7FFFu + ((u >> 16) & 1u);   // round-to-nearest-even
  return (unsigned short)(u >> 16);
}
__device__ __forceinline__ void gload_lds16(const void* g, void* l) {
  __builtin_amdgcn_global_load_lds(
      (const __attribute__((address_space(1))) unsigned int*)(uintptr_t)g,
      (__attribute__((address_space(3))) unsigned int*)l, 16, 0, 0);
}

// ------- transpose+cast both weights: f32 [E][K][N] -> bf16 [E][N][K] -------
__global__ __launch_bounds__(256) void transpose_both(
    const float* __restrict__ w1, const float* __restrict__ w2,
    unsigned short* __restrict__ w1T, unsigned short* __restrict__ w2T) {
  __shared__ float t[64][65];
  const int which = blockIdx.z >> 3, e = blockIdx.z & 7;
  const int K = which ? FF : DM, Nn = which ? DM : FF;
  const int nt = which ? blockIdx.y : blockIdx.x;
  const int kt = which ? blockIdx.x : blockIdx.y;
  const float* s = (which ? w2 : w1) + (size_t)e * K * Nn;
  unsigned short* d = (which ? w2T : w1T) + (size_t)e * Nn * K;
  const int n0 = nt * 64, k0 = kt * 64;
  const int tid = threadIdx.x;
  for (int p = tid; p < 1024; p += 256) {
    int r = p >> 4, c4 = (p & 15) * 4;
    float4 v = *(const float4*)(s + (size_t)(k0 + r) * Nn + n0 + c4);
    t[c4 + 0][r] = v.x; t[c4 + 1][r] = v.y;
    t[c4 + 2][r] = v.z; t[c4 + 3][r] = v.w;
  }
  __syncthreads();
  for (int p = tid; p < 512; p += 256) {
    int c = p >> 3, r8 = (p & 7) * 8;
    unsigned short tmp[8];
#pragma unroll
    for (int i = 0; i < 8; ++i) tmp[i] = f2bf(t[c][r8 + i]);
    *(uint4*)(d + (size_t)(n0 + c) * K + k0 + r8) = *(const uint4*)tmp;
  }
}

// ---------------- LN + centroid scores (f32 in, bf16 nrm out) ---------------
__global__ __launch_bounds__(256) void ln_scores_k(
    const float* __restrict__ x, const float* __restrict__ g,
    const float* __restrict__ b, const float* __restrict__ cent,
    unsigned short* __restrict__ nrm, float* __restrict__ scores) {
  const int t = blockIdx.x, tid = threadIdx.x;
  const int lane = tid & 63, w = tid >> 6;
  float4 v = ((const float4*)(x + (size_t)t * DM))[tid];
  float f0 = v.x, f1 = v.y, f2 = v.z, f3 = v.w;
  float s = f0 + f1 + f2 + f3;
  float sq = f0 * f0 + f1 * f1 + f2 * f2 + f3 * f3;
#pragma unroll
  for (int o = 32; o > 0; o >>= 1) { s += __shfl_xor(s, o); sq += __shfl_xor(sq, o); }
  __shared__ float red[8];
  if (lane == 0) { red[w] = s; red[4 + w] = sq; }
  __syncthreads();
  float S = red[0] + red[1] + red[2] + red[3];
  float SQ = red[4] + red[5] + red[6] + red[7];
  float mu = S * (1.0f / DM);
  float var = SQ * (1.0f / DM) - mu * mu;
  float rstd = rsqrtf(var + 1e-5f);
  float4 gv = ((const float4*)g)[tid];
  float4 bv = ((const float4*)b)[tid];
  float n0 = (f0 - mu) * rstd * gv.x + bv.x;
  float n1 = (f1 - mu) * rstd * gv.y + bv.y;
  float n2 = (f2 - mu) * rstd * gv.z + bv.z;
  float n3 = (f3 - mu) * rstd * gv.w + bv.w;
  ushort4 o4;
  o4.x = f2bf(n0); o4.y = f2bf(n1); o4.z = f2bf(n2); o4.w = f2bf(n3);
  ((ushort4*)(nrm + (size_t)t * DM))[tid] = o4;
  __shared__ float sred[4];
  for (int e = 0; e < NE; ++e) {
    float4 cv = ((const float4*)(cent + e * DM))[tid];
    float p = n0 * cv.x + n1 * cv.y + n2 * cv.z + n3 * cv.w;
#pragma unroll
    for (int o = 32; o > 0; o >>= 1) p += __shfl_xor(p, o);
    if (lane == 0) sred[w] = p;
    __syncthreads();
    if (tid == 0) scores[(size_t)t * NE + e] = sred[0] + sred[1] + sred[2] + sred[3];
    __syncthreads();
  }
}

// ---------------- balanced assignment (greedy per expert, exact top_k) ------
__global__ __launch_bounds__(1024) void assign_k(const float* __restrict__ scores,
                                                 int* __restrict__ tok) {
  __shared__ unsigned key[T_TOK];
  __shared__ unsigned char taken[T_TOK];
  __shared__ unsigned hist[256];
  __shared__ unsigned scan[256];
  __shared__ unsigned wsum[16];
  __shared__ unsigned prefS, needS, cntS, remS;
  const int tid = threadIdx.x, lane = tid & 63, w = tid >> 6;
  for (int i = tid; i < T_TOK; i += 1024) taken[i] = 0;
  __syncthreads();
  for (int e = 0; e < NE; ++e) {
    for (int i = tid; i < T_TOK; i += 1024) {
      unsigned k = 0;
      if (!taken[i]) {
        unsigned bb = __float_as_uint(scores[(size_t)i * NE + e]);
        k = (bb & 0x80000000u) ? ~bb : (bb | 0x80000000u);  // order-preserving
      }
      key[i] = k;
    }
    if (tid == 0) { prefS = 0u; needS = CAP; cntS = 0u; }
    __syncthreads();
#pragma unroll
    for (int pass = 0; pass < 4; ++pass) {
      const int shift = 24 - 8 * pass;
      if (tid < 256) hist[tid] = 0u;
      unsigned pref = prefS, need = needS;
      unsigned hmask = (pass == 0) ? 0u : (0xFFFFFFFFu << (shift + 8));
      __syncthreads();
      for (int i = tid; i < T_TOK; i += 1024) {
        unsigned k = key[i];
        if ((k & hmask) == (pref & hmask)) atomicAdd(&hist[(k >> shift) & 255u], 1u);
      }
      __syncthreads();
      if (tid < 256) scan[tid] = hist[tid];
      __syncthreads();
      for (int off2 = 1; off2 < 256; off2 <<= 1) {   // suffix inclusive scan
        unsigned vv = 0;
        if (tid < 256) { vv = scan[tid]; if (tid + off2 < 256) vv += scan[tid + off2]; }
        __syncthreads();
        if (tid < 256) scan[tid] = vv;
        __syncthreads();
      }
      if (tid < 256) {
        unsigned incl = scan[tid], excl = incl - hist[tid];
        if (excl < need && incl >= need) {
          prefS = (pref & hmask) | (((unsigned)tid) << shift);
          needS = need - excl;
        }
      }
      __syncthreads();
    }
    const unsigned P = prefS;
    const unsigned need = needS;
    for (int i = tid; i < T_TOK; i += 1024) {
      if (key[i] > P) {
        unsigned pos = atomicAdd(&cntS, 1u);
        tok[e * CAP + pos] = i;
        taken[i] = 1;
      }
    }
    if (tid == 0) remS = need;
    __syncthreads();
    for (int ch = 0; ch < 8; ++ch) {   // ==pivot by lowest index (jax ties)
      int i = ch * 1024 + tid;
      bool flag = (key[i] == P);
      unsigned long long ball = __ballot(flag);
      if (lane == 0) wsum[w] = (unsigned)__popcll(ball);
      unsigned myc = (unsigned)__popcll(ball & ((1ull << lane) - 1ull));
      __syncthreads();
      unsigned base = 0, tot = 0;
      for (int j2 = 0; j2 < 16; ++j2) { unsigned u = wsum[j2]; tot += u; if (j2 < w) base += u; }
      unsigned rem = remS;
      if (flag && (base + myc) < rem) {
        unsigned pos = atomicAdd(&cntS, 1u);
        tok[e * CAP + pos] = i;
        taken[i] = 1;
      }
      __syncthreads();
      if (tid == 0) remS = (rem > tot) ? (rem - tot) : 0u;
      __syncthreads();
    }
    __syncthreads();
  }
}

// ------- 8-phase MFMA GEMM: C = A[MxK] * Bt[NxK]^T --------------------------
// BM=256, BK=64 (2 k-halves), dbuf over K-tile parity. Per phase: ds_read
// fragment subtile + stage one (op,khalf) half + [vmcnt@p3/p7] + barrier +
// lgkmcnt(0) + MH*NR MFMA + barrier. Dataflow proof in session notes.
// EPI==1: +bias, gelu -> bf16 h1;  EPI==2: +bias +xres, scatter f32 out.
template <int EPI, bool GATHER, int K, int N, int BN, int WM, int WN>
__global__ __launch_bounds__(512, 2) void gemm_8ph(
    const unsigned short* __restrict__ A, const unsigned short* __restrict__ Bt,
    const float* __restrict__ bias, const int* __restrict__ tok,
    const float* __restrict__ xres, void* __restrict__ Cout) {
  constexpr int BM = 256;
  constexpr int NT = K / 64;             // K-tiles (even)
  constexpr int NITER = NT / 2;
  constexpr int RM = BM / WM, RN = BN / WN;
  constexpr int MR = RM / 16, NR = RN / 16, MH = MR / 2;
  constexpr int ALD = 2;                 // A gloads/thread per k-half
  constexpr int BLD = BN / 128;          // B gloads/thread per k-half
  constexpr int ASH = BM * 32;           // shorts per A k-half region
  constexpr int BSH = BN * 32;
  constexpr int BUFS = 2 * ASH + 2 * BSH;
  __shared__ __align__(16) unsigned short lds[2 * BUFS];
  __shared__ int tokl[BM];

  const int e  = blockIdx.z;
  const int n0 = blockIdx.x * BN, m0 = blockIdx.y * BM;
  const int tid = threadIdx.x, lane = tid & 63, w = tid >> 6;
  const int wr = w / WN, wc = w % WN;
  const int lr = lane & 15, lk = lane >> 4;

  for (int i = tid; i < BM; i += 512) tokl[i] = tok[e * CAP + m0 + i];
  __syncthreads();

  // per-thread staging sources (16B chunks, source-side XOR swizzle)
  const unsigned short* aptr[ALD];
  const unsigned short* bptr[BLD];
  const unsigned short* Be = Bt + (size_t)e * N * K + (size_t)n0 * K;
#pragma unroll
  for (int i = 0; i < ALD; ++i) {
    int c = i * 512 + tid, row = c >> 2, sp = c & 3;
    int s = sp ^ ((row >> 1) & 3);
    size_t grow = GATHER ? (size_t)tokl[row] : (size_t)(e * CAP + m0 + row);
    aptr[i] = A + grow * K + s * 8;
  }
#pragma unroll
  for (int i = 0; i < BLD; ++i) {
    int c = i * 512 + tid, row = c >> 2, sp = c & 3;
    int s = sp ^ ((row >> 1) & 3);
    bptr[i] = Be + (size_t)row * K + s * 8;
  }
  auto stageA = [&](int tile, int kh) {
#pragma unroll
    for (int i = 0; i < ALD; ++i)
      gload_lds16(aptr[i] + tile * 64 + kh * 32,
                  lds + (size_t)(tile & 1) * BUFS + kh * ASH + (i * 512 + tid) * 8);
  };
  auto stageB = [&](int tile, int kh) {
#pragma unroll
    for (int i = 0; i < BLD; ++i)
      gload_lds16(bptr[i] + tile * 64 + kh * 32,
                  lds + (size_t)(tile & 1) * BUFS + 2 * ASH + kh * BSH + (i * 512 + tid) * 8);
  };

  // fragment LDS offsets (shorts, within a k-half region); swizzle dep on lr only
  const int swz = (lr >> 1) & 3;
  const int afo = (wr * RM + lr) * 32 + (lk ^ swz) * 8;
  const int bfo = (wc * RN + lr) * 32 + (lk ^ swz) * 8;

  f32x4 acc[MR][NR] = {};

  // prologue: tile0 all 4 halves, tile1 k0 halves; allow tile1 in flight
  stageA(0, 0); stageB(0, 0); stageA(0, 1); stageB(0, 1);
  stageA(1, 0); stageB(1, 0);
  asm volatile("s_waitcnt vmcnt(%0)" :: "i"(ALD + BLD) : "memory");
  __builtin_amdgcn_s_barrier();

#pragma unroll 1
  for (int it = 0; it < NITER; ++it) {
    const int ta = 2 * it, tb = 2 * it + 1;
    bf16x8 bfr[NR], af[MH];
#pragma unroll
    for (int p = 0; p < 8; ++p) {
      const int buf = p >> 2, kh = (p >> 1) & 1, mh = p & 1;
      // ---- ds_read fragments for this phase
      if (mh == 0) {
#pragma unroll
        for (int ni = 0; ni < NR; ++ni)
          bfr[ni] = *(const bf16x8*)(lds + (size_t)buf * BUFS + 2 * ASH +
                                     kh * BSH + bfo + ni * 512);
      }
#pragma unroll
      for (int j = 0; j < MH; ++j)
        af[j] = *(const bf16x8*)(lds + (size_t)buf * BUFS + kh * ASH + afo +
                                 (mh * MH + j) * 512);
      // ---- stage plan (region-liveness + vmcnt-coverage verified)
      if (p == 0)      {                       stageA(tb, 1);     stageB(tb, 1); }
      else if (p == 2) { if (ta + 2 < NT)      stageA(ta + 2, 0); }
      else if (p == 3) { if (ta + 2 < NT)      stageB(ta + 2, 0); }
      else if (p == 4) { if (ta + 2 < NT)    { stageA(ta + 2, 1); stageB(ta + 2, 1); } }
      else if (p == 6) { if (tb + 2 < NT)      stageA(tb + 2, 0); }
      else if (p == 7) { if (tb + 2 < NT)      stageB(tb + 2, 0); }
      if (p == 3 || p == 7)
        asm volatile("s_waitcnt vmcnt(%0)" :: "i"(ALD + BLD) : "memory");
      __builtin_amdgcn_s_barrier();
      asm volatile("s_waitcnt lgkmcnt(0)" ::: "memory");
      __builtin_amdgcn_sched_barrier(0);
      __builtin_amdgcn_s_setprio(1);
#pragma unroll
      for (int j = 0; j < MH; ++j)
#pragma unroll
        for (int ni = 0; ni < NR; ++ni)
          acc[mh * MH + j][ni] = __builtin_amdgcn_mfma_f32_16x16x32_bf16(
              af[j], bfr[ni], acc[mh * MH + j][ni], 0, 0, 0);
      __builtin_amdgcn_s_setprio(0);
      __builtin_amdgcn_s_barrier();
    }
  }

  // ---- epilogue
  const int lg = lane >> 4;
#pragma unroll
  for (int ni = 0; ni < NR; ++ni) {
    const int n = n0 + wc * RN + ni * 16 + lr;
    const float bb = bias[e * N + n];
#pragma unroll
    for (int mi = 0; mi < MR; ++mi) {
#pragma unroll
      for (int r = 0; r < 4; ++r) {
        const int ml = wr * RM + mi * 16 + lg * 4 + r;
        float v = acc[mi][ni][r] + bb;
        if (EPI == 1) {
          float z = 1.5957691216f * v + 0.07135481283f * v * v * v;
          float gl = v / (1.0f + __expf(-z));
          ((unsigned short*)Cout)[(size_t)(e * CAP + m0 + ml) * N + n] = f2bf(gl);
        } else {
          const int token = tokl[ml];
          v += xres[(size_t)token * DM + n];
          ((float*)Cout)[(size_t)token * (size_t)N + n] = v;
        }
      }
    }
  }
}

// ---------------- launch ----------------------------------------------------
extern "C" void kernel_launch(void* const* d_in, const int* in_sizes, int n_in,
                              void* d_out, int out_size, void* d_ws, size_t ws_size,
                              hipStream_t stream) {
  const float* x    = (const float*)d_in[0];
  const float* cent = (const float*)d_in[1];
  const float* ln_g = (const float*)d_in[2];
  const float* ln_b = (const float*)d_in[3];
  const float* w1   = (const float*)d_in[4];
  const float* b1   = (const float*)d_in[5];
  const float* w2   = (const float*)d_in[6];
  const float* b2   = (const float*)d_in[7];
  float* out = (float*)d_out;

  char* ws = (char*)d_ws;
  size_t off = 0;
  unsigned short* w1T = (unsigned short*)(ws + off); off += (size_t)NE * FF * DM * 2;
  unsigned short* w2T = (unsigned short*)(ws + off); off += (size_t)NE * DM * FF * 2;
  unsigned short* nrm = (unsigned short*)(ws + off); off += (size_t)T_TOK * DM * 2;
  unsigned short* h1  = (unsigned short*)(ws + off); off += (size_t)T_TOK * FF * 2;
  float* scores       = (float*)(ws + off);          off += (size_t)T_TOK * NE * 4;
  int* tok            = (int*)(ws + off);            off += (size_t)T_TOK * 4;

  transpose_both<<<dim3(64, 16, 16), 256, 0, stream>>>(w1, w2, w1T, w2T);
  ln_scores_k<<<dim3(T_TOK), 256, 0, stream>>>(x, ln_g, ln_b, cent, nrm, scores);
  assign_k<<<dim3(1), 1024, 0, stream>>>(scores, tok);
  // GEMM1: [E] nrm-gather[1024x1024] x w1T[4096x1024]^T -> h1 (gelu)
  gemm_8ph<1, true, DM, FF, 256, 2, 4>
      <<<dim3(FF / 256, CAP / 256, NE), 512, 0, stream>>>(nrm, w1T, b1, tok, nullptr, h1);
  // GEMM2: [E] h1[1024x4096] x w2T[1024x4096]^T -> out (+bias+res, scatter)
  gemm_8ph<2, false, FF, DM, 128, 4, 2>
      <<<dim3(DM / 128, CAP / 256, NE), 512, 0, stream>>>(h1, w2T, b2, tok, x, out);
}

// Round 5
// 375.773 us; speedup vs baseline: 1.3407x; 1.2113x over previous
//
#include <hip/hip_runtime.h>
#include <hip/hip_bf16.h>
#include <stdint.h>

// BaseLayer MoE block. I/O f32, GEMMs bf16 MFMA. T=8192, D=1024, F=4096, E=8.
// R5: assignment rewritten (1 histogram + wave-scan pivot + candidate
// compaction + bitmap tie-break) and fused with the weight transpose into one
// fat kernel (block 0 = assign, blocks 1.. = 128x128 transpose tiles).
// GEMMs: unchanged 8-phase schedule from R4.

#define T_TOK 8192
#define DM    1024
#define FF    4096
#define NE    8
#define CAP   1024

typedef __attribute__((ext_vector_type(8))) __bf16 bf16x8;
typedef __attribute__((ext_vector_type(4))) float  f32x4;

__device__ __forceinline__ unsigned short f2bf(float f) {
  unsigned u = __float_as_uint(f);
  u += 0x7FFFu + ((u >> 16) & 1u);   // round-to-nearest-even
  return (unsigned short)(u >> 16);
}
__device__ __forceinline__ void gload_lds16(const void* g, void* l) {
  __builtin_amdgcn_global_load_lds(
      (const __attribute__((address_space(1))) unsigned int*)(uintptr_t)g,
      (__attribute__((address_space(3))) unsigned int*)l, 16, 0, 0);
}

// ---------------- LN + centroid scores (scores stored [E][T]) ---------------
__global__ __launch_bounds__(256) void ln_scores_k(
    const float* __restrict__ x, const float* __restrict__ g,
    const float* __restrict__ b, const float* __restrict__ cent,
    unsigned short* __restrict__ nrm, float* __restrict__ scores) {
  const int t = blockIdx.x, tid = threadIdx.x;
  const int lane = tid & 63, w = tid >> 6;
  float4 v = ((const float4*)(x + (size_t)t * DM))[tid];
  float f0 = v.x, f1 = v.y, f2 = v.z, f3 = v.w;
  float s = f0 + f1 + f2 + f3;
  float sq = f0 * f0 + f1 * f1 + f2 * f2 + f3 * f3;
#pragma unroll
  for (int o = 32; o > 0; o >>= 1) { s += __shfl_xor(s, o); sq += __shfl_xor(sq, o); }
  __shared__ float red[8];
  if (lane == 0) { red[w] = s; red[4 + w] = sq; }
  __syncthreads();
  float S = red[0] + red[1] + red[2] + red[3];
  float SQ = red[4] + red[5] + red[6] + red[7];
  float mu = S * (1.0f / DM);
  float var = SQ * (1.0f / DM) - mu * mu;
  float rstd = rsqrtf(var + 1e-5f);
  float4 gv = ((const float4*)g)[tid];
  float4 bv = ((const float4*)b)[tid];
  float n0 = (f0 - mu) * rstd * gv.x + bv.x;
  float n1 = (f1 - mu) * rstd * gv.y + bv.y;
  float n2 = (f2 - mu) * rstd * gv.z + bv.z;
  float n3 = (f3 - mu) * rstd * gv.w + bv.w;
  ushort4 o4;
  o4.x = f2bf(n0); o4.y = f2bf(n1); o4.z = f2bf(n2); o4.w = f2bf(n3);
  ((ushort4*)(nrm + (size_t)t * DM))[tid] = o4;
  __shared__ float sred[4];
  for (int e = 0; e < NE; ++e) {
    float4 cv = ((const float4*)(cent + e * DM))[tid];
    float p = n0 * cv.x + n1 * cv.y + n2 * cv.z + n3 * cv.w;
#pragma unroll
    for (int o = 32; o > 0; o >>= 1) p += __shfl_xor(p, o);
    if (lane == 0) sred[w] = p;
    __syncthreads();
    if (tid == 0) scores[(size_t)e * T_TOK + t] = sred[0] + sred[1] + sred[2] + sred[3];
    __syncthreads();
  }
}

// ---- wave-0 helpers for the assignment (64 lanes, lockstep) ----------------
// Suffix-scan hist[256] (4 buckets/lane), find bucket b: excl(b)<need<=incl(b);
// S[0]=need (in/out), S[1]=pivot bucket (out).
__device__ __forceinline__ void pivot_scan(const unsigned* hist, unsigned* S) {
  const int l = threadIdx.x;
  unsigned v0 = hist[4 * l], v1 = hist[4 * l + 1];
  unsigned v2 = hist[4 * l + 2], v3 = hist[4 * l + 3];
  unsigned own = v0 + v1 + v2 + v3;
  unsigned s = own;
#pragma unroll
  for (int off = 1; off < 64; off <<= 1) {
    unsigned t = __shfl_down(s, off);
    if (l + off < 64) s += t;
  }
  unsigned i3 = (s - own) + v3;
  unsigned i2 = i3 + v2;
  unsigned i1 = i2 + v1;
  unsigned i0 = i1 + v0;
  unsigned need = S[0];
  if (i0 >= need && i0 - v0 < need) { S[1] = 4 * l + 0; S[0] = need - (i0 - v0); }
  if (i1 >= need && i1 - v1 < need) { S[1] = 4 * l + 1; S[0] = need - (i1 - v1); }
  if (i2 >= need && i2 - v2 < need) { S[1] = 4 * l + 2; S[0] = need - (i2 - v2); }
  if (i3 >= need && i3 - v3 < need) { S[1] = 4 * l + 3; S[0] = need - (i3 - v3); }
}
// Select S[0] lowest-index set bits of bmap (8192 bits), emit via S[2] counter.
__device__ __forceinline__ void tie_select(const unsigned* bmap, unsigned* S,
                                           int* tokdst, unsigned char* taken) {
  const int l = threadIdx.x;
  unsigned wds[4] = {bmap[4 * l], bmap[4 * l + 1], bmap[4 * l + 2], bmap[4 * l + 3]};
  unsigned cnt = __popc(wds[0]) + __popc(wds[1]) + __popc(wds[2]) + __popc(wds[3]);
  unsigned p = cnt;
#pragma unroll
  for (int off = 1; off < 64; off <<= 1) {
    unsigned t = __shfl_up(p, off);
    if (l >= off) p += t;
  }
  unsigned base = p - cnt;                 // exclusive prefix of set-bit counts
  const unsigned r = S[0];
#pragma unroll
  for (int c = 0; c < 4; ++c) {
    unsigned word = wds[c];
    while (word && base < r) {
      int b = __ffs(word) - 1; word &= word - 1;
      int i = (4 * l + c) * 32 + b;
      unsigned pp = atomicAdd(&S[2], 1u);
      tokdst[pp] = i; taken[i] = 1;
      ++base;
    }
    base += __popc(word);
  }
}

// ---- assignment body: greedy per-expert exact top-C (jax top_k ties) -------
__device__ void assign_body(const float* __restrict__ scores,
                            int* __restrict__ tok, char* smem) {
  unsigned*       key   = (unsigned*)smem;                   // 32 KB
  unsigned short* candA = (unsigned short*)(smem + 32768);   // 16 KB
  unsigned short* candB = (unsigned short*)(smem + 49152);   // 16 KB
  unsigned char*  taken = (unsigned char*)(smem + 65536);    //  8 KB
  unsigned*       hist  = (unsigned*)(smem + 73728);         //  1 KB
  unsigned*       bmap  = (unsigned*)(smem + 74752);         //  1 KB
  unsigned*       S     = (unsigned*)(smem + 75776);         // scalars
  const int tid = threadIdx.x;
  for (int i = tid; i < T_TOK; i += 1024) taken[i] = 0;
  __syncthreads();
  for (int e = 0; e < NE; ++e) {
    const float* se = scores + (size_t)e * T_TOK;
    if (tid < 256) hist[tid] = 0;
    if (tid == 0) { S[0] = CAP; S[2] = 0; S[4] = 0; }
    __syncthreads();
#pragma unroll
    for (int j = 0; j < 8; ++j) {          // keys + level-0 histogram
      int i = j * 1024 + tid;
      unsigned k = 0;
      if (!taken[i]) {
        unsigned bb = __float_as_uint(se[i]);
        k = (bb & 0x80000000u) ? ~bb : (bb | 0x80000000u);   // order-preserving
      }
      key[i] = k;
      atomicAdd(&hist[k >> 24], 1u);
    }
    __syncthreads();
    if (tid < 64) pivot_scan(hist, S);
    __syncthreads();
    {                                       // level-0 emit winners + compact
      const unsigned pb = S[1];
#pragma unroll
      for (int j = 0; j < 8; ++j) {
        int i = j * 1024 + tid;
        unsigned by = key[i] >> 24;
        if (by > pb) {
          unsigned p = atomicAdd(&S[2], 1u);
          tok[e * CAP + p] = i; taken[i] = 1;
        } else if (by == pb) {
          unsigned q = atomicAdd(&S[4], 1u);
          candA[q] = (unsigned short)i;
        }
      }
    }
    __syncthreads();
    unsigned short* cur = candA;
    unsigned short* nxt = candB;
    for (int shift = 16; shift >= 0; shift -= 8) {   // refine on candidates
      const unsigned m = S[4];
      __syncthreads();
      if (tid < 256) hist[tid] = 0;
      if (tid == 0) S[4] = 0;
      __syncthreads();
      for (unsigned q = tid; q < m; q += 1024)
        atomicAdd(&hist[(key[cur[q]] >> shift) & 255u], 1u);
      __syncthreads();
      if (tid < 64) pivot_scan(hist, S);
      __syncthreads();
      const unsigned pb = S[1];
      for (unsigned q = tid; q < m; q += 1024) {
        unsigned i = cur[q];
        unsigned by = (key[i] >> shift) & 255u;
        if (by > pb) {
          unsigned p = atomicAdd(&S[2], 1u);
          tok[e * CAP + p] = (int)i; taken[i] = 1;
        } else if (by == pb) {
          unsigned t2 = atomicAdd(&S[4], 1u);
          nxt[t2] = (unsigned short)i;
        }
      }
      __syncthreads();
      unsigned short* tmp = cur; cur = nxt; nxt = tmp;
    }
    // ties: keys exactly equal to pivot; take S[0] of them by LOWEST index
    if (tid < 256) bmap[tid] = 0;
    __syncthreads();
    {
      const unsigned m = S[4];
      for (unsigned q = tid; q < m; q += 1024) {
        unsigned i = cur[q];
        atomicOr(&bmap[i >> 5], 1u << (i & 31));
      }
    }
    __syncthreads();
    if (tid < 64) tie_select(bmap, S, tok + e * CAP, taken);
    __syncthreads();
  }
}

// ---- fat kernel: block 0 = assignment; blocks 1.. = weight transpose -------
// transpose: f32 [E][K][N] -> bf16 [E][N][K], 128x128 tiles, 1024 threads.
__global__ __launch_bounds__(1024) void fat_assign_transpose(
    const float* __restrict__ scores, int* __restrict__ tok,
    const float* __restrict__ w1, const float* __restrict__ w2,
    unsigned short* __restrict__ w1T, unsigned short* __restrict__ w2T) {
  __shared__ __align__(16) char smem[77824];
  if (blockIdx.x == 0) { assign_body(scores, tok, smem); return; }
  const int tix = blockIdx.x - 1;
  const int which = tix >> 11;           // 2048 tiles each
  const int r = tix & 2047;
  const int e = r >> 8;
  const int rr = r & 255;
  int K, N, nt, kt;
  const float* s;
  unsigned short* d;
  if (which == 0) { K = DM; N = FF; nt = rr & 31; kt = rr >> 5; s = w1; d = w1T; }
  else            { K = FF; N = DM; nt = rr & 7;  kt = rr >> 3; s = w2; d = w2T; }
  s += (size_t)e * K * N;
  d += (size_t)e * N * K;
  const int n0 = nt * 128, k0 = kt * 128;
  const int tid = threadIdx.x;
  float (*t)[132] = (float (*)[132])smem;
#pragma unroll
  for (int j = 0; j < 4; ++j) {          // 4096 float4 loads
    int c = j * 1024 + tid;
    int row = c >> 5, c4 = (c & 31) * 4;
    float4 v = *(const float4*)(s + (size_t)(k0 + row) * N + n0 + c4);
    t[c4 + 0][row] = v.x; t[c4 + 1][row] = v.y;
    t[c4 + 2][row] = v.z; t[c4 + 3][row] = v.w;
  }
  __syncthreads();
#pragma unroll
  for (int j = 0; j < 2; ++j) {          // 2048 uint4 (8xbf16) stores
    int q = j * 1024 + tid;
    int col = q >> 4, r8 = (q & 15) * 8;
    unsigned short tmp[8];
#pragma unroll
    for (int i = 0; i < 8; ++i) tmp[i] = f2bf(t[col][r8 + i]);
    *(uint4*)(d + (size_t)(n0 + col) * K + k0 + r8) = *(const uint4*)tmp;
  }
}

// ------- 8-phase MFMA GEMM: C = A[MxK] * Bt[NxK]^T (unchanged from R4) ------
template <int EPI, bool GATHER, int K, int N, int BN, int WM, int WN>
__global__ __launch_bounds__(512, 2) void gemm_8ph(
    const unsigned short* __restrict__ A, const unsigned short* __restrict__ Bt,
    const float* __restrict__ bias, const int* __restrict__ tok,
    const float* __restrict__ xres, void* __restrict__ Cout) {
  constexpr int BM = 256;
  constexpr int NT = K / 64;
  constexpr int NITER = NT / 2;
  constexpr int RM = BM / WM, RN = BN / WN;
  constexpr int MR = RM / 16, NR = RN / 16, MH = MR / 2;
  constexpr int ALD = 2;
  constexpr int BLD = BN / 128;
  constexpr int ASH = BM * 32;
  constexpr int BSH = BN * 32;
  constexpr int BUFS = 2 * ASH + 2 * BSH;
  __shared__ __align__(16) unsigned short lds[2 * BUFS];
  __shared__ int tokl[BM];

  const int e  = blockIdx.z;
  const int n0 = blockIdx.x * BN, m0 = blockIdx.y * BM;
  const int tid = threadIdx.x, lane = tid & 63, w = tid >> 6;
  const int wr = w / WN, wc = w % WN;
  const int lr = lane & 15, lk = lane >> 4;

  for (int i = tid; i < BM; i += 512) tokl[i] = tok[e * CAP + m0 + i];
  __syncthreads();

  const unsigned short* aptr[ALD];
  const unsigned short* bptr[BLD];
  const unsigned short* Be = Bt + (size_t)e * N * K + (size_t)n0 * K;
#pragma unroll
  for (int i = 0; i < ALD; ++i) {
    int c = i * 512 + tid, row = c >> 2, sp = c & 3;
    int s = sp ^ ((row >> 1) & 3);
    size_t grow = GATHER ? (size_t)tokl[row] : (size_t)(e * CAP + m0 + row);
    aptr[i] = A + grow * K + s * 8;
  }
#pragma unroll
  for (int i = 0; i < BLD; ++i) {
    int c = i * 512 + tid, row = c >> 2, sp = c & 3;
    int s = sp ^ ((row >> 1) & 3);
    bptr[i] = Be + (size_t)row * K + s * 8;
  }
  auto stageA = [&](int tile, int kh) {
#pragma unroll
    for (int i = 0; i < ALD; ++i)
      gload_lds16(aptr[i] + tile * 64 + kh * 32,
                  lds + (size_t)(tile & 1) * BUFS + kh * ASH + (i * 512 + tid) * 8);
  };
  auto stageB = [&](int tile, int kh) {
#pragma unroll
    for (int i = 0; i < BLD; ++i)
      gload_lds16(bptr[i] + tile * 64 + kh * 32,
                  lds + (size_t)(tile & 1) * BUFS + 2 * ASH + kh * BSH + (i * 512 + tid) * 8);
  };

  const int swz = (lr >> 1) & 3;
  const int afo = (wr * RM + lr) * 32 + (lk ^ swz) * 8;
  const int bfo = (wc * RN + lr) * 32 + (lk ^ swz) * 8;

  f32x4 acc[MR][NR] = {};

  stageA(0, 0); stageB(0, 0); stageA(0, 1); stageB(0, 1);
  stageA(1, 0); stageB(1, 0);
  asm volatile("s_waitcnt vmcnt(%0)" :: "i"(ALD + BLD) : "memory");
  __builtin_amdgcn_s_barrier();

#pragma unroll 1
  for (int it = 0; it < NITER; ++it) {
    const int ta = 2 * it, tb = 2 * it + 1;
    bf16x8 bfr[NR], af[MH];
#pragma unroll
    for (int p = 0; p < 8; ++p) {
      const int buf = p >> 2, kh = (p >> 1) & 1, mh = p & 1;
      if (mh == 0) {
#pragma unroll
        for (int ni = 0; ni < NR; ++ni)
          bfr[ni] = *(const bf16x8*)(lds + (size_t)buf * BUFS + 2 * ASH +
                                     kh * BSH + bfo + ni * 512);
      }
#pragma unroll
      for (int j = 0; j < MH; ++j)
        af[j] = *(const bf16x8*)(lds + (size_t)buf * BUFS + kh * ASH + afo +
                                 (mh * MH + j) * 512);
      if (p == 0)      {                       stageA(tb, 1);     stageB(tb, 1); }
      else if (p == 2) { if (ta + 2 < NT)      stageA(ta + 2, 0); }
      else if (p == 3) { if (ta + 2 < NT)      stageB(ta + 2, 0); }
      else if (p == 4) { if (ta + 2 < NT)    { stageA(ta + 2, 1); stageB(ta + 2, 1); } }
      else if (p == 6) { if (tb + 2 < NT)      stageA(tb + 2, 0); }
      else if (p == 7) { if (tb + 2 < NT)      stageB(tb + 2, 0); }
      if (p == 3 || p == 7)
        asm volatile("s_waitcnt vmcnt(%0)" :: "i"(ALD + BLD) : "memory");
      __builtin_amdgcn_s_barrier();
      asm volatile("s_waitcnt lgkmcnt(0)" ::: "memory");
      __builtin_amdgcn_sched_barrier(0);
      __builtin_amdgcn_s_setprio(1);
#pragma unroll
      for (int j = 0; j < MH; ++j)
#pragma unroll
        for (int ni = 0; ni < NR; ++ni)
          acc[mh * MH + j][ni] = __builtin_amdgcn_mfma_f32_16x16x32_bf16(
              af[j], bfr[ni], acc[mh * MH + j][ni], 0, 0, 0);
      __builtin_amdgcn_s_setprio(0);
      __builtin_amdgcn_s_barrier();
    }
  }

  const int lg = lane >> 4;
#pragma unroll
  for (int ni = 0; ni < NR; ++ni) {
    const int n = n0 + wc * RN + ni * 16 + lr;
    const float bb = bias[e * N + n];
#pragma unroll
    for (int mi = 0; mi < MR; ++mi) {
#pragma unroll
      for (int r = 0; r < 4; ++r) {
        const int ml = wr * RM + mi * 16 + lg * 4 + r;
        float v = acc[mi][ni][r] + bb;
        if (EPI == 1) {
          float z = 1.5957691216f * v + 0.07135481283f * v * v * v;
          float gl = v / (1.0f + __expf(-z));
          ((unsigned short*)Cout)[(size_t)(e * CAP + m0 + ml) * N + n] = f2bf(gl);
        } else {
          const int token = tokl[ml];
          v += xres[(size_t)token * DM + n];
          ((float*)Cout)[(size_t)token * (size_t)N + n] = v;
        }
      }
    }
  }
}

// ---------------- launch ----------------------------------------------------
extern "C" void kernel_launch(void* const* d_in, const int* in_sizes, int n_in,
                              void* d_out, int out_size, void* d_ws, size_t ws_size,
                              hipStream_t stream) {
  const float* x    = (const float*)d_in[0];
  const float* cent = (const float*)d_in[1];
  const float* ln_g = (const float*)d_in[2];
  const float* ln_b = (const float*)d_in[3];
  const float* w1   = (const float*)d_in[4];
  const float* b1   = (const float*)d_in[5];
  const float* w2   = (const float*)d_in[6];
  const float* b2   = (const float*)d_in[7];
  float* out = (float*)d_out;

  char* ws = (char*)d_ws;
  size_t off = 0;
  unsigned short* w1T = (unsigned short*)(ws + off); off += (size_t)NE * FF * DM * 2;
  unsigned short* w2T = (unsigned short*)(ws + off); off += (size_t)NE * DM * FF * 2;
  unsigned short* nrm = (unsigned short*)(ws + off); off += (size_t)T_TOK * DM * 2;
  unsigned short* h1  = (unsigned short*)(ws + off); off += (size_t)T_TOK * FF * 2;
  float* scores       = (float*)(ws + off);          off += (size_t)NE * T_TOK * 4;
  int* tok            = (int*)(ws + off);            off += (size_t)T_TOK * 4;

  ln_scores_k<<<dim3(T_TOK), 256, 0, stream>>>(x, ln_g, ln_b, cent, nrm, scores);
  // block 0: assignment; blocks 1..4096: transpose w1 (2048 tiles) + w2 (2048)
  fat_assign_transpose<<<dim3(1 + 4096), 1024, 0, stream>>>(
      scores, tok, w1, w2, w1T, w2T);
  // GEMM1: [E] nrm-gather[1024x1024] x w1T[4096x1024]^T -> h1 (gelu)
  gemm_8ph<1, true, DM, FF, 256, 2, 4>
      <<<dim3(FF / 256, CAP / 256, NE), 512, 0, stream>>>(nrm, w1T, b1, tok, nullptr, h1);
  // GEMM2: [E] h1[1024x4096] x w2T[1024x4096]^T -> out (+bias+res, scatter)
  gemm_8ph<2, false, FF, DM, 128, 4, 2>
      <<<dim3(DM / 128, CAP / 256, NE), 512, 0, stream>>>(h1, w2T, b2, tok, x, out);
}

// Round 6
// 346.728 us; speedup vs baseline: 1.4530x; 1.0838x over previous
//
#include <hip/hip_runtime.h>
#include <hip/hip_bf16.h>
#include <stdint.h>

// BaseLayer MoE block. I/O f32, GEMMs bf16 MFMA. T=8192, D=1024, F=4096, E=8.
// R6: transpose bank-conflict fix (4x 64x64 [64][65] quadrants — proven R4
// pattern) + XCD-aware chunked block swizzle on both GEMMs (T1).

#define T_TOK 8192
#define DM    1024
#define FF    4096
#define NE    8
#define CAP   1024

typedef __attribute__((ext_vector_type(8))) __bf16 bf16x8;
typedef __attribute__((ext_vector_type(4))) float  f32x4;

__device__ __forceinline__ unsigned short f2bf(float f) {
  unsigned u = __float_as_uint(f);
  u += 0x7FFFu + ((u >> 16) & 1u);   // round-to-nearest-even
  return (unsigned short)(u >> 16);
}
__device__ __forceinline__ void gload_lds16(const void* g, void* l) {
  __builtin_amdgcn_global_load_lds(
      (const __attribute__((address_space(1))) unsigned int*)(uintptr_t)g,
      (__attribute__((address_space(3))) unsigned int*)l, 16, 0, 0);
}

// ---------------- LN + centroid scores (scores stored [E][T]) ---------------
__global__ __launch_bounds__(256) void ln_scores_k(
    const float* __restrict__ x, const float* __restrict__ g,
    const float* __restrict__ b, const float* __restrict__ cent,
    unsigned short* __restrict__ nrm, float* __restrict__ scores) {
  const int t = blockIdx.x, tid = threadIdx.x;
  const int lane = tid & 63, w = tid >> 6;
  float4 v = ((const float4*)(x + (size_t)t * DM))[tid];
  float f0 = v.x, f1 = v.y, f2 = v.z, f3 = v.w;
  float s = f0 + f1 + f2 + f3;
  float sq = f0 * f0 + f1 * f1 + f2 * f2 + f3 * f3;
#pragma unroll
  for (int o = 32; o > 0; o >>= 1) { s += __shfl_xor(s, o); sq += __shfl_xor(sq, o); }
  __shared__ float red[8];
  if (lane == 0) { red[w] = s; red[4 + w] = sq; }
  __syncthreads();
  float S = red[0] + red[1] + red[2] + red[3];
  float SQ = red[4] + red[5] + red[6] + red[7];
  float mu = S * (1.0f / DM);
  float var = SQ * (1.0f / DM) - mu * mu;
  float rstd = rsqrtf(var + 1e-5f);
  float4 gv = ((const float4*)g)[tid];
  float4 bv = ((const float4*)b)[tid];
  float n0 = (f0 - mu) * rstd * gv.x + bv.x;
  float n1 = (f1 - mu) * rstd * gv.y + bv.y;
  float n2 = (f2 - mu) * rstd * gv.z + bv.z;
  float n3 = (f3 - mu) * rstd * gv.w + bv.w;
  ushort4 o4;
  o4.x = f2bf(n0); o4.y = f2bf(n1); o4.z = f2bf(n2); o4.w = f2bf(n3);
  ((ushort4*)(nrm + (size_t)t * DM))[tid] = o4;
  __shared__ float sred[4];
  for (int e = 0; e < NE; ++e) {
    float4 cv = ((const float4*)(cent + e * DM))[tid];
    float p = n0 * cv.x + n1 * cv.y + n2 * cv.z + n3 * cv.w;
#pragma unroll
    for (int o = 32; o > 0; o >>= 1) p += __shfl_xor(p, o);
    if (lane == 0) sred[w] = p;
    __syncthreads();
    if (tid == 0) scores[(size_t)e * T_TOK + t] = sred[0] + sred[1] + sred[2] + sred[3];
    __syncthreads();
  }
}

// ---- wave-0 helpers for the assignment (64 lanes, lockstep) ----------------
__device__ __forceinline__ void pivot_scan(const unsigned* hist, unsigned* S) {
  const int l = threadIdx.x;
  unsigned v0 = hist[4 * l], v1 = hist[4 * l + 1];
  unsigned v2 = hist[4 * l + 2], v3 = hist[4 * l + 3];
  unsigned own = v0 + v1 + v2 + v3;
  unsigned s = own;
#pragma unroll
  for (int off = 1; off < 64; off <<= 1) {
    unsigned t = __shfl_down(s, off);
    if (l + off < 64) s += t;
  }
  unsigned i3 = (s - own) + v3;
  unsigned i2 = i3 + v2;
  unsigned i1 = i2 + v1;
  unsigned i0 = i1 + v0;
  unsigned need = S[0];
  if (i0 >= need && i0 - v0 < need) { S[1] = 4 * l + 0; S[0] = need - (i0 - v0); }
  if (i1 >= need && i1 - v1 < need) { S[1] = 4 * l + 1; S[0] = need - (i1 - v1); }
  if (i2 >= need && i2 - v2 < need) { S[1] = 4 * l + 2; S[0] = need - (i2 - v2); }
  if (i3 >= need && i3 - v3 < need) { S[1] = 4 * l + 3; S[0] = need - (i3 - v3); }
}
__device__ __forceinline__ void tie_select(const unsigned* bmap, unsigned* S,
                                           int* tokdst, unsigned char* taken) {
  const int l = threadIdx.x;
  unsigned wds[4] = {bmap[4 * l], bmap[4 * l + 1], bmap[4 * l + 2], bmap[4 * l + 3]};
  unsigned cnt = __popc(wds[0]) + __popc(wds[1]) + __popc(wds[2]) + __popc(wds[3]);
  unsigned p = cnt;
#pragma unroll
  for (int off = 1; off < 64; off <<= 1) {
    unsigned t = __shfl_up(p, off);
    if (l >= off) p += t;
  }
  unsigned base = p - cnt;
  const unsigned r = S[0];
#pragma unroll
  for (int c = 0; c < 4; ++c) {
    unsigned word = wds[c];
    while (word && base < r) {
      int b = __ffs(word) - 1; word &= word - 1;
      int i = (4 * l + c) * 32 + b;
      unsigned pp = atomicAdd(&S[2], 1u);
      tokdst[pp] = i; taken[i] = 1;
      ++base;
    }
    base += __popc(word);
  }
}

// ---- assignment body: greedy per-expert exact top-C (jax top_k ties) -------
__device__ void assign_body(const float* __restrict__ scores,
                            int* __restrict__ tok, char* smem) {
  unsigned*       key   = (unsigned*)smem;                   // 32 KB
  unsigned short* candA = (unsigned short*)(smem + 32768);   // 16 KB
  unsigned short* candB = (unsigned short*)(smem + 49152);   // 16 KB
  unsigned char*  taken = (unsigned char*)(smem + 65536);    //  8 KB
  unsigned*       hist  = (unsigned*)(smem + 73728);         //  1 KB
  unsigned*       bmap  = (unsigned*)(smem + 74752);         //  1 KB
  unsigned*       S     = (unsigned*)(smem + 75776);         // scalars
  const int tid = threadIdx.x;
  for (int i = tid; i < T_TOK; i += 1024) taken[i] = 0;
  __syncthreads();
  for (int e = 0; e < NE; ++e) {
    const float* se = scores + (size_t)e * T_TOK;
    if (tid < 256) hist[tid] = 0;
    if (tid == 0) { S[0] = CAP; S[2] = 0; S[4] = 0; }
    __syncthreads();
#pragma unroll
    for (int j = 0; j < 8; ++j) {
      int i = j * 1024 + tid;
      unsigned k = 0;
      if (!taken[i]) {
        unsigned bb = __float_as_uint(se[i]);
        k = (bb & 0x80000000u) ? ~bb : (bb | 0x80000000u);   // order-preserving
      }
      key[i] = k;
      atomicAdd(&hist[k >> 24], 1u);
    }
    __syncthreads();
    if (tid < 64) pivot_scan(hist, S);
    __syncthreads();
    {
      const unsigned pb = S[1];
#pragma unroll
      for (int j = 0; j < 8; ++j) {
        int i = j * 1024 + tid;
        unsigned by = key[i] >> 24;
        if (by > pb) {
          unsigned p = atomicAdd(&S[2], 1u);
          tok[e * CAP + p] = i; taken[i] = 1;
        } else if (by == pb) {
          unsigned q = atomicAdd(&S[4], 1u);
          candA[q] = (unsigned short)i;
        }
      }
    }
    __syncthreads();
    unsigned short* cur = candA;
    unsigned short* nxt = candB;
    for (int shift = 16; shift >= 0; shift -= 8) {
      const unsigned m = S[4];
      __syncthreads();
      if (tid < 256) hist[tid] = 0;
      if (tid == 0) S[4] = 0;
      __syncthreads();
      for (unsigned q = tid; q < m; q += 1024)
        atomicAdd(&hist[(key[cur[q]] >> shift) & 255u], 1u);
      __syncthreads();
      if (tid < 64) pivot_scan(hist, S);
      __syncthreads();
      const unsigned pb = S[1];
      for (unsigned q = tid; q < m; q += 1024) {
        unsigned i = cur[q];
        unsigned by = (key[i] >> shift) & 255u;
        if (by > pb) {
          unsigned p = atomicAdd(&S[2], 1u);
          tok[e * CAP + p] = (int)i; taken[i] = 1;
        } else if (by == pb) {
          unsigned t2 = atomicAdd(&S[4], 1u);
          nxt[t2] = (unsigned short)i;
        }
      }
      __syncthreads();
      unsigned short* tmp = cur; cur = nxt; nxt = tmp;
    }
    if (tid < 256) bmap[tid] = 0;
    __syncthreads();
    {
      const unsigned m = S[4];
      for (unsigned q = tid; q < m; q += 1024) {
        unsigned i = cur[q];
        atomicOr(&bmap[i >> 5], 1u << (i & 31));
      }
    }
    __syncthreads();
    if (tid < 64) tie_select(bmap, S, tok + e * CAP, taken);
    __syncthreads();
  }
}

// ---- fat kernel: block 0 = assignment; blocks 1.. = weight transpose -------
// 128x128 tile as 4 independent 64x64 quadrants, each float[64][65] (bank
// stride 1 -> conflict-free; proven R4 pattern).
__global__ __launch_bounds__(1024) void fat_assign_transpose(
    const float* __restrict__ scores, int* __restrict__ tok,
    const float* __restrict__ w1, const float* __restrict__ w2,
    unsigned short* __restrict__ w1T, unsigned short* __restrict__ w2T) {
  __shared__ __align__(16) char smem[77824];
  if (blockIdx.x == 0) { assign_body(scores, tok, smem); return; }
  const int tix = blockIdx.x - 1;
  const int which = tix >> 11;           // 2048 tiles each
  const int r = tix & 2047;
  const int e = r >> 8;
  const int rr = r & 255;
  int K, N, nt, kt;
  const float* s;
  unsigned short* d;
  if (which == 0) { K = DM; N = FF; nt = rr & 31; kt = rr >> 5; s = w1; d = w1T; }
  else            { K = FF; N = DM; nt = rr & 7;  kt = rr >> 3; s = w2; d = w2T; }
  s += (size_t)e * K * N;
  d += (size_t)e * N * K;
  const int q = threadIdx.x >> 8, t2 = threadIdx.x & 255;
  const int k0 = kt * 128 + (q >> 1) * 64;
  const int n0 = nt * 128 + (q & 1) * 64;
  float (*t)[65] = (float (*)[65])(smem + q * 16640);
  for (int p = t2; p < 1024; p += 256) {
    int rw = p >> 4, c4 = (p & 15) * 4;
    float4 v = *(const float4*)(s + (size_t)(k0 + rw) * N + n0 + c4);
    t[c4 + 0][rw] = v.x; t[c4 + 1][rw] = v.y;
    t[c4 + 2][rw] = v.z; t[c4 + 3][rw] = v.w;
  }
  __syncthreads();
  for (int p = t2; p < 512; p += 256) {
    int c = p >> 3, r8 = (p & 7) * 8;
    unsigned short tmp[8];
#pragma unroll
    for (int i = 0; i < 8; ++i) tmp[i] = f2bf(t[c][r8 + i]);
    *(uint4*)(d + (size_t)(n0 + c) * K + k0 + r8) = *(const uint4*)tmp;
  }
}

// ------- 8-phase MFMA GEMM: C = A[MxK] * Bt[NxK]^T + XCD swizzle ------------
template <int EPI, bool GATHER, int K, int N, int BN, int WM, int WN>
__global__ __launch_bounds__(512, 2) void gemm_8ph(
    const unsigned short* __restrict__ A, const unsigned short* __restrict__ Bt,
    const float* __restrict__ bias, const int* __restrict__ tok,
    const float* __restrict__ xres, void* __restrict__ Cout) {
  constexpr int BM = 256;
  constexpr int NT = K / 64;
  constexpr int NITER = NT / 2;
  constexpr int RM = BM / WM, RN = BN / WN;
  constexpr int MR = RM / 16, NR = RN / 16, MH = MR / 2;
  constexpr int ALD = 2;
  constexpr int BLD = BN / 128;
  constexpr int ASH = BM * 32;
  constexpr int BSH = BN * 32;
  constexpr int BUFS = 2 * ASH + 2 * BSH;
  __shared__ __align__(16) unsigned short lds[2 * BUFS];
  __shared__ int tokl[BM];

  // XCD-aware chunked swizzle (nwg % 8 == 0): each XCD gets a contiguous
  // chunk of the (x,y,z) tile space -> L2 reuse of shared A/B panels.
  const int flat = blockIdx.x + gridDim.x * (blockIdx.y + gridDim.y * blockIdx.z);
  const int nwg = gridDim.x * gridDim.y * gridDim.z;
  const int nf = (flat & 7) * (nwg >> 3) + (flat >> 3);
  const int bx = nf % gridDim.x;
  const int rem = nf / gridDim.x;
  const int e  = rem / gridDim.y;
  const int n0 = bx * BN, m0 = (rem % gridDim.y) * BM;

  const int tid = threadIdx.x, lane = tid & 63, w = tid >> 6;
  const int wr = w / WN, wc = w % WN;
  const int lr = lane & 15, lk = lane >> 4;

  for (int i = tid; i < BM; i += 512) tokl[i] = tok[e * CAP + m0 + i];
  __syncthreads();

  const unsigned short* aptr[ALD];
  const unsigned short* bptr[BLD];
  const unsigned short* Be = Bt + (size_t)e * N * K + (size_t)n0 * K;
#pragma unroll
  for (int i = 0; i < ALD; ++i) {
    int c = i * 512 + tid, row = c >> 2, sp = c & 3;
    int s = sp ^ ((row >> 1) & 3);
    size_t grow = GATHER ? (size_t)tokl[row] : (size_t)(e * CAP + m0 + row);
    aptr[i] = A + grow * K + s * 8;
  }
#pragma unroll
  for (int i = 0; i < BLD; ++i) {
    int c = i * 512 + tid, row = c >> 2, sp = c & 3;
    int s = sp ^ ((row >> 1) & 3);
    bptr[i] = Be + (size_t)row * K + s * 8;
  }
  auto stageA = [&](int tile, int kh) {
#pragma unroll
    for (int i = 0; i < ALD; ++i)
      gload_lds16(aptr[i] + tile * 64 + kh * 32,
                  lds + (size_t)(tile & 1) * BUFS + kh * ASH + (i * 512 + tid) * 8);
  };
  auto stageB = [&](int tile, int kh) {
#pragma unroll
    for (int i = 0; i < BLD; ++i)
      gload_lds16(bptr[i] + tile * 64 + kh * 32,
                  lds + (size_t)(tile & 1) * BUFS + 2 * ASH + kh * BSH + (i * 512 + tid) * 8);
  };

  const int swz = (lr >> 1) & 3;
  const int afo = (wr * RM + lr) * 32 + (lk ^ swz) * 8;
  const int bfo = (wc * RN + lr) * 32 + (lk ^ swz) * 8;

  f32x4 acc[MR][NR] = {};

  stageA(0, 0); stageB(0, 0); stageA(0, 1); stageB(0, 1);
  stageA(1, 0); stageB(1, 0);
  asm volatile("s_waitcnt vmcnt(%0)" :: "i"(ALD + BLD) : "memory");
  __builtin_amdgcn_s_barrier();

#pragma unroll 1
  for (int it = 0; it < NITER; ++it) {
    const int ta = 2 * it, tb = 2 * it + 1;
    bf16x8 bfr[NR], af[MH];
#pragma unroll
    for (int p = 0; p < 8; ++p) {
      const int buf = p >> 2, kh = (p >> 1) & 1, mh = p & 1;
      if (mh == 0) {
#pragma unroll
        for (int ni = 0; ni < NR; ++ni)
          bfr[ni] = *(const bf16x8*)(lds + (size_t)buf * BUFS + 2 * ASH +
                                     kh * BSH + bfo + ni * 512);
      }
#pragma unroll
      for (int j = 0; j < MH; ++j)
        af[j] = *(const bf16x8*)(lds + (size_t)buf * BUFS + kh * ASH + afo +
                                 (mh * MH + j) * 512);
      if (p == 0)      {                       stageA(tb, 1);     stageB(tb, 1); }
      else if (p == 2) { if (ta + 2 < NT)      stageA(ta + 2, 0); }
      else if (p == 3) { if (ta + 2 < NT)      stageB(ta + 2, 0); }
      else if (p == 4) { if (ta + 2 < NT)    { stageA(ta + 2, 1); stageB(ta + 2, 1); } }
      else if (p == 6) { if (tb + 2 < NT)      stageA(tb + 2, 0); }
      else if (p == 7) { if (tb + 2 < NT)      stageB(tb + 2, 0); }
      if (p == 3 || p == 7)
        asm volatile("s_waitcnt vmcnt(%0)" :: "i"(ALD + BLD) : "memory");
      __builtin_amdgcn_s_barrier();
      asm volatile("s_waitcnt lgkmcnt(0)" ::: "memory");
      __builtin_amdgcn_sched_barrier(0);
      __builtin_amdgcn_s_setprio(1);
#pragma unroll
      for (int j = 0; j < MH; ++j)
#pragma unroll
        for (int ni = 0; ni < NR; ++ni)
          acc[mh * MH + j][ni] = __builtin_amdgcn_mfma_f32_16x16x32_bf16(
              af[j], bfr[ni], acc[mh * MH + j][ni], 0, 0, 0);
      __builtin_amdgcn_s_setprio(0);
      __builtin_amdgcn_s_barrier();
    }
  }

  const int lg = lane >> 4;
#pragma unroll
  for (int ni = 0; ni < NR; ++ni) {
    const int n = n0 + wc * RN + ni * 16 + lr;
    const float bb = bias[e * N + n];
#pragma unroll
    for (int mi = 0; mi < MR; ++mi) {
#pragma unroll
      for (int r = 0; r < 4; ++r) {
        const int ml = wr * RM + mi * 16 + lg * 4 + r;
        float v = acc[mi][ni][r] + bb;
        if (EPI == 1) {
          float z = 1.5957691216f * v + 0.07135481283f * v * v * v;
          float gl = v / (1.0f + __expf(-z));
          ((unsigned short*)Cout)[(size_t)(e * CAP + m0 + ml) * N + n] = f2bf(gl);
        } else {
          const int token = tokl[ml];
          v += xres[(size_t)token * DM + n];
          ((float*)Cout)[(size_t)token * (size_t)N + n] = v;
        }
      }
    }
  }
}

// ---------------- launch ----------------------------------------------------
extern "C" void kernel_launch(void* const* d_in, const int* in_sizes, int n_in,
                              void* d_out, int out_size, void* d_ws, size_t ws_size,
                              hipStream_t stream) {
  const float* x    = (const float*)d_in[0];
  const float* cent = (const float*)d_in[1];
  const float* ln_g = (const float*)d_in[2];
  const float* ln_b = (const float*)d_in[3];
  const float* w1   = (const float*)d_in[4];
  const float* b1   = (const float*)d_in[5];
  const float* w2   = (const float*)d_in[6];
  const float* b2   = (const float*)d_in[7];
  float* out = (float*)d_out;

  char* ws = (char*)d_ws;
  size_t off = 0;
  unsigned short* w1T = (unsigned short*)(ws + off); off += (size_t)NE * FF * DM * 2;
  unsigned short* w2T = (unsigned short*)(ws + off); off += (size_t)NE * DM * FF * 2;
  unsigned short* nrm = (unsigned short*)(ws + off); off += (size_t)T_TOK * DM * 2;
  unsigned short* h1  = (unsigned short*)(ws + off); off += (size_t)T_TOK * FF * 2;
  float* scores       = (float*)(ws + off);          off += (size_t)NE * T_TOK * 4;
  int* tok            = (int*)(ws + off);            off += (size_t)T_TOK * 4;

  ln_scores_k<<<dim3(T_TOK), 256, 0, stream>>>(x, ln_g, ln_b, cent, nrm, scores);
  fat_assign_transpose<<<dim3(1 + 4096), 1024, 0, stream>>>(
      scores, tok, w1, w2, w1T, w2T);
  gemm_8ph<1, true, DM, FF, 256, 2, 4>
      <<<dim3(FF / 256, CAP / 256, NE), 512, 0, stream>>>(nrm, w1T, b1, tok, nullptr, h1);
  gemm_8ph<2, false, FF, DM, 128, 4, 2>
      <<<dim3(DM / 128, CAP / 256, NE), 512, 0, stream>>>(h1, w2T, b2, tok, x, out);
}